// Round 12
// baseline (133.798 us; speedup 1.0000x reference)
//
#include <hip/hip_runtime.h>
#include <math.h>

#define RANK 33
#define D 32            // rank-1 (space dims)
#define N_ENT 50000
#define N_REL 500
#define NQ 2000
#define W_PAD 50176     // embT row stride (98 * 512)
#define NQ_PAD 2048     // lhsT row stride
#define MT 200          // m per y-block in k_scores (grid y = 10)

#define EXP_BLK 196     // ceil(50000/256) thread-per-entity blocks
#define QRY_BLK 500     // 2000 queries / 4 waves
#define NRM_BLK 125     // 500 relations / 4 waves

typedef float f2v __attribute__((ext_vector_type(2)));

__device__ __forceinline__ float waveReduceSum(float v) {
    #pragma unroll
    for (int off = 32; off > 0; off >>= 1)
        v += __shfl_xor(v, off, 64);
    return v;
}

// ---------------- K1 (fused prep): expmap-all | query-transform | rel-norms.
__global__ void k_prep(const float* __restrict__ ent,
                       const float* __restrict__ rot_raw,
                       const float* __restrict__ boosts,
                       const int* __restrict__ queries,
                       float* __restrict__ embT, float* __restrict__ lhsT,
                       float* __restrict__ rotF, float* __restrict__ boostN) {
    int bid = blockIdx.x;
    if (bid < EXP_BLK) {
        // ---- expmap0, thread-per-entity -> embT[33][W_PAD] (dim-major, coalesced)
        int n = bid * blockDim.x + threadIdx.x;
        if (n >= N_ENT) return;
        const float* u = ent + (size_t)n * RANK;
        float v[RANK];
        float en2 = 0.f;
        #pragma unroll
        for (int k = 0; k < RANK; ++k) { v[k] = u[k]; en2 += v[k] * v[k]; }
        float scale = fminf(1.0f, 2.0f / fmaxf(sqrtf(en2), 1e-12f));
        #pragma unroll
        for (int k = 0; k < RANK; ++k) v[k] *= scale;
        float sp2 = 0.f;
        #pragma unroll
        for (int k = 1; k < RANK; ++k) sp2 += v[k] * v[k];
        float nomin = sqrtf(fmaxf(sp2 - v[0] * v[0], 1e-8f));
        float s = sinhf(nomin) / nomin;
        float t2 = 0.f;
        #pragma unroll
        for (int k = 1; k < RANK; ++k) { v[k] *= s; t2 += v[k] * v[k]; }
        embT[n] = sqrtf(1.0f + t2);
        #pragma unroll
        for (int k = 1; k < RANK; ++k)
            embT[(size_t)k * W_PAD + n] = v[k];
    } else if (bid < EXP_BLK + QRY_BLK) {
        // ---- per-query transform, wave-per-query -> lhsT[33][NQ_PAD] (lhs_neg)
        int wave = (bid - EXP_BLK) * 4 + (threadIdx.x >> 6);
        int lane = threadIdx.x & 63;
        if (wave >= NQ) return;
        int h = queries[wave * 3 + 0];
        int r = queries[wave * 3 + 1];
        const float* u = ent + (long)h * RANK;
        float uv = (lane < RANK) ? u[lane] : 0.0f;
        float en = sqrtf(waveReduceSum(uv * uv));
        float scale = fminf(1.0f, 2.0f / fmaxf(en, 1e-12f));
        uv *= scale;
        float sp2 = waveReduceSum((lane >= 1 && lane < RANK) ? uv * uv : 0.0f);
        float u0 = __shfl(uv, 0, 64);
        float nomin = sqrtf(fmaxf(sp2 - u0 * u0, 1e-8f));
        float s = sinhf(nomin) / nomin;
        float sv = s * uv;
        float t2 = waveReduceSum((lane >= 1 && lane < RANK) ? sv * sv : 0.0f);
        float lhs_t = sqrtf(1.0f + t2);
        float x = __shfl(sv, (lane + 1) & 63, 64);
        if (lane >= D) x = 0.0f;
        // x^T (H_0..H_31) = H_31(..(H_0 x))  (each H_k symmetric)
        const float* rr = rot_raw + (long)r * D * D;
        for (int k = 0; k < D; ++k) {
            float g = 0.0f;
            if (lane < D) {
                float w = rr[k * D + lane];
                g = 0.5f * w * (1.0f + erff(w * 0.70710678118654752f)); // exact gelu
            }
            float dvx = waveReduceSum(g * x);
            float n   = waveReduceSum(g * g);
            x -= (2.0f * dvx / n) * g;
        }
        float b = 0.0f;
        if (lane < D) b = tanhf(boosts[(long)r * D + lane]) * (1.0f / 33.0f);
        float b2   = waveReduceSum(b * b);
        float bdot = waveReduceSum(b * x);
        float zeta = 1.0f / (sqrtf(1.0f - b2) + 1e-8f);
        float x0 = zeta * lhs_t - zeta * bdot;
        float xr = -zeta * lhs_t * b + x + (zeta - 1.0f) / (b2 + 1e-9f) * b * bdot;
        if (lane < D) lhsT[(size_t)(1 + lane) * NQ_PAD + wave] = xr;
        if (lane == 0) lhsT[wave] = -x0;
    } else {
        // ---- per-relation norms (raw rot Frobenius + boost L2)
        int wave = (bid - EXP_BLK - QRY_BLK) * 4 + (threadIdx.x >> 6);
        int lane = threadIdx.x & 63;
        if (wave >= N_REL) return;
        const float* rr = rot_raw + (long)wave * (D * D);
        float s = 0.0f;
        #pragma unroll
        for (int i = 0; i < (D * D) / 64; ++i) {
            float w = rr[i * 64 + lane];
            s += w * w;
        }
        s = waveReduceSum(s);
        float sb = 0.0f;
        if (lane < D) { float w = boosts[(long)wave * D + lane]; sb = w * w; }
        sb = waveReduceSum(sb);
        if (lane == 0) { rotF[wave] = sqrtf(s); boostN[wave] = sqrtf(sb); }
    }
}

// ---------------- K2: reg[i,j] = rotF[j] + boostN[i]
__global__ void k_reg(const float* __restrict__ rotF, const float* __restrict__ boostN,
                      float* __restrict__ out) {
    int idx = blockIdx.x * blockDim.x + threadIdx.x;
    if (idx >= N_REL * N_REL) return;
    int i = idx / N_REL;
    int j = idx - i * N_REL;
    out[idx] = rotF[j] + boostN[i];
}

// ---------------- K3: scores = 2 - 2 * lhs_neg @ emb^T  (fp32, PACKED math).
// Thread owns 2 adjacent n (f2v); accumulators are f2v so the inner loop emits
// v_pk_fma_f32 (2 FMA/instr) -> half the VALU issue of R11. lhsT loads are
// wave-uniform (scalar-promoted). Wave store = 512 B contiguous per m row.
__global__ __launch_bounds__(256, 4)
void k_scores(const float* __restrict__ lhsT,
              const float* __restrict__ embT,
              float* __restrict__ out) {
    int t = threadIdx.x;
    int n = blockIdx.x * 512 + t * 2;
    if (n >= N_ENT) return;
    int m0 = blockIdx.y * MT;
    f2v e[RANK];
    #pragma unroll
    for (int k = 0; k < RANK; ++k)
        e[k] = *(const f2v*)(embT + (size_t)k * W_PAD + n);
    for (int mt = m0; mt < m0 + MT; mt += 4) {
        f2v a0 = {0.f, 0.f}, a1 = {0.f, 0.f}, a2 = {0.f, 0.f}, a3 = {0.f, 0.f};
        #pragma unroll
        for (int k = 0; k < RANK; ++k) {
            float4 l = *(const float4*)(lhsT + k * NQ_PAD + mt);
            f2v ek = e[k];
            a0 += ek * l.x;       // v_pk_fma_f32
            a1 += ek * l.y;
            a2 += ek * l.z;
            a3 += ek * l.w;
        }
        f2v s0 = {2.f - 2.f * a0.x, 2.f - 2.f * a0.y};
        f2v s1 = {2.f - 2.f * a1.x, 2.f - 2.f * a1.y};
        f2v s2 = {2.f - 2.f * a2.x, 2.f - 2.f * a2.y};
        f2v s3 = {2.f - 2.f * a3.x, 2.f - 2.f * a3.y};
        __builtin_nontemporal_store(s0, (f2v*)(out + (size_t)(mt + 0) * N_ENT + n));
        __builtin_nontemporal_store(s1, (f2v*)(out + (size_t)(mt + 1) * N_ENT + n));
        __builtin_nontemporal_store(s2, (f2v*)(out + (size_t)(mt + 2) * N_ENT + n));
        __builtin_nontemporal_store(s3, (f2v*)(out + (size_t)(mt + 3) * N_ENT + n));
    }
}

extern "C" void kernel_launch(void* const* d_in, const int* in_sizes, int n_in,
                              void* d_out, int out_size, void* d_ws, size_t ws_size,
                              hipStream_t stream) {
    const float* ent     = (const float*)d_in[0];   // 50000 x 33
    const float* rot     = (const float*)d_in[1];   // 500 x 32 x 32
    const float* boosts  = (const float*)d_in[2];   // 500 x 32
    const int*   queries = (const int*)d_in[3];     // 2000 x 3 (h, r, t)
    float* out = (float*)d_out;                     // scores (2000x50000) ++ reg (500x500)

    float* ws     = (float*)d_ws;
    float* embT   = ws;                               // 33 * 50176 floats
    float* lhsT   = ws + (size_t)RANK * W_PAD;        // 33 * 2048 floats
    float* rotF   = lhsT + (size_t)RANK * NQ_PAD;     // 500
    float* boostN = rotF + N_REL;                     // 500

    hipLaunchKernelGGL(k_prep, dim3(EXP_BLK + QRY_BLK + NRM_BLK), dim3(256), 0, stream,
                       ent, rot, boosts, queries, embT, lhsT, rotF, boostN);
    hipLaunchKernelGGL(k_reg, dim3((N_REL * N_REL + 255) / 256), dim3(256), 0, stream,
                       rotF, boostN, out + (size_t)NQ * N_ENT);
    hipLaunchKernelGGL(k_scores, dim3(98, NQ / MT), dim3(256), 0, stream,
                       lhsT, embT, out);
}